// Round 1
// baseline (104.908 us; speedup 1.0000x reference)
//
#include <hip/hip_runtime.h>

// i0e(x) = exp(-|x|) * I0(x), Abramowitz & Stegun 9.8.1 / 9.8.2,
// matching the JAX reference's branch structure exactly.
__device__ __forceinline__ float i0e_scalar(float x) {
    float ax = fabsf(x);

    // ---- small branch: exp(-ax) * poly((ax/3.75)^2), ascending-coeff Horner
    float t = ax * (1.0f / 3.75f);
    t = t * t;
    float ps = 0.0045813f;
    ps = fmaf(ps, t, 0.0360768f);
    ps = fmaf(ps, t, 0.2659732f);
    ps = fmaf(ps, t, 1.2067492f);
    ps = fmaf(ps, t, 3.0899424f);
    ps = fmaf(ps, t, 3.5156229f);
    ps = fmaf(ps, t, 1.0f);
    float sm = __expf(-ax) * ps;

    // ---- large branch: poly(3.75/ax_l) / sqrt(ax_l), ax_l = max(ax, 3.75)
    float axl = fmaxf(ax, 3.75f);
    float u = 3.75f * __builtin_amdgcn_rcpf(axl);   // v_rcp_f32, ~1 ulp
    float pl = 0.00392377f;
    pl = fmaf(pl, u, -0.01647633f);
    pl = fmaf(pl, u, 0.02635537f);
    pl = fmaf(pl, u, -0.02057706f);
    pl = fmaf(pl, u, 0.00916281f);
    pl = fmaf(pl, u, -0.00157565f);
    pl = fmaf(pl, u, 0.00225319f);
    pl = fmaf(pl, u, 0.01328592f);
    pl = fmaf(pl, u, 0.39894228f);
    float lg = pl * __builtin_amdgcn_rsqf(axl);     // v_rsq_f32

    return (ax <= 3.75f) ? sm : lg;
}

__global__ __launch_bounds__(256) void ive_i0e_kernel(
        const float* __restrict__ in, float* __restrict__ out, int n) {
    const int n4 = n >> 2;
    const int stride = gridDim.x * blockDim.x;
    const float4* __restrict__ in4 = reinterpret_cast<const float4*>(in);
    float4* __restrict__ out4 = reinterpret_cast<float4*>(out);

    for (int i = blockIdx.x * blockDim.x + threadIdx.x; i < n4; i += stride) {
        float4 v = in4[i];
        float4 r;
        r.x = i0e_scalar(v.x);
        r.y = i0e_scalar(v.y);
        r.z = i0e_scalar(v.z);
        r.w = i0e_scalar(v.w);
        out4[i] = r;
    }

    // tail (n % 4 != 0 — not hit for 64*1024*1024 but keep it correct)
    const int tail = n4 << 2;
    for (int i = tail + blockIdx.x * blockDim.x + threadIdx.x; i < n; i += stride) {
        out[i] = i0e_scalar(in[i]);
    }
}

extern "C" void kernel_launch(void* const* d_in, const int* in_sizes, int n_in,
                              void* d_out, int out_size, void* d_ws, size_t ws_size,
                              hipStream_t stream) {
    const float* z = (const float*)d_in[0];
    float* out = (float*)d_out;
    const int n = in_sizes[0];

    const int block = 256;
    int grid = (n / 4 + block - 1) / block;
    if (grid > 2048) grid = 2048;   // grid-stride; ~8 blocks/CU across 256 CUs
    if (grid < 1) grid = 1;

    ive_i0e_kernel<<<grid, block, 0, stream>>>(z, out, n);
}

// Round 3
// 100.586 us; speedup vs baseline: 1.0430x; 1.0430x over previous
//
#include <hip/hip_runtime.h>

// Native clang vector type — accepted by __builtin_nontemporal_{load,store},
// lowers to global_{load,store}_dwordx4 with nt.
typedef float f32x4 __attribute__((ext_vector_type(4)));

// i0e(x) = exp(-|x|) * I0(x), Abramowitz & Stegun 9.8.1 / 9.8.2,
// matching the JAX reference's branch structure exactly.
__device__ __forceinline__ float i0e_scalar(float x) {
    float ax = fabsf(x);

    // ---- small branch: exp(-ax) * poly((ax/3.75)^2), ascending-coeff Horner
    float t = ax * (1.0f / 3.75f);
    t = t * t;
    float ps = 0.0045813f;
    ps = fmaf(ps, t, 0.0360768f);
    ps = fmaf(ps, t, 0.2659732f);
    ps = fmaf(ps, t, 1.2067492f);
    ps = fmaf(ps, t, 3.0899424f);
    ps = fmaf(ps, t, 3.5156229f);
    ps = fmaf(ps, t, 1.0f);
    float sm = __expf(-ax) * ps;

    // ---- large branch: poly(3.75/ax_l) / sqrt(ax_l), ax_l = max(ax, 3.75)
    float axl = fmaxf(ax, 3.75f);
    float u = 3.75f * __builtin_amdgcn_rcpf(axl);   // v_rcp_f32, ~1 ulp
    float pl = 0.00392377f;
    pl = fmaf(pl, u, -0.01647633f);
    pl = fmaf(pl, u, 0.02635537f);
    pl = fmaf(pl, u, -0.02057706f);
    pl = fmaf(pl, u, 0.00916281f);
    pl = fmaf(pl, u, -0.00157565f);
    pl = fmaf(pl, u, 0.00225319f);
    pl = fmaf(pl, u, 0.01328592f);
    pl = fmaf(pl, u, 0.39894228f);
    float lg = pl * __builtin_amdgcn_rsqf(axl);     // v_rsq_f32

    return (ax <= 3.75f) ? sm : lg;
}

__device__ __forceinline__ f32x4 i0e_vec4(f32x4 v) {
    f32x4 r;
    r.x = i0e_scalar(v.x);
    r.y = i0e_scalar(v.y);
    r.z = i0e_scalar(v.z);
    r.w = i0e_scalar(v.w);
    return r;
}

__global__ __launch_bounds__(256) void ive_i0e_kernel(
        const float* __restrict__ in, float* __restrict__ out, int n) {
    const int n4 = n >> 2;
    const int tid = blockIdx.x * blockDim.x + threadIdx.x;
    const int stride = gridDim.x * blockDim.x;
    const f32x4* __restrict__ in4 = reinterpret_cast<const f32x4*>(in);
    f32x4* __restrict__ out4 = reinterpret_cast<f32x4*>(out);

    // 2x-unrolled grid-stride: both nt loads in flight before either compute.
    int i = tid;
    for (; i + stride < n4; i += 2 * stride) {
        f32x4 a = __builtin_nontemporal_load(&in4[i]);
        f32x4 b = __builtin_nontemporal_load(&in4[i + stride]);
        f32x4 ra = i0e_vec4(a);
        f32x4 rb = i0e_vec4(b);
        __builtin_nontemporal_store(ra, &out4[i]);
        __builtin_nontemporal_store(rb, &out4[i + stride]);
    }
    if (i < n4) {
        f32x4 a = __builtin_nontemporal_load(&in4[i]);
        __builtin_nontemporal_store(i0e_vec4(a), &out4[i]);
    }

    // scalar tail (n % 4 != 0 — not hit for 64*1024*1024 but keep it correct)
    const int tail = n4 << 2;
    for (int j = tail + tid; j < n; j += stride) {
        out[j] = i0e_scalar(in[j]);
    }
}

extern "C" void kernel_launch(void* const* d_in, const int* in_sizes, int n_in,
                              void* d_out, int out_size, void* d_ws, size_t ws_size,
                              hipStream_t stream) {
    const float* z = (const float*)d_in[0];
    float* out = (float*)d_out;
    const int n = in_sizes[0];

    const int block = 256;
    int grid = (n / 4 + block - 1) / block;
    if (grid > 2048) grid = 2048;   // grid-stride; 8 blocks/CU across 256 CUs
    if (grid < 1) grid = 1;

    ive_i0e_kernel<<<grid, block, 0, stream>>>(z, out, n);
}